// Round 1
// baseline (672.637 us; speedup 1.0000x reference)
//
#include <hip/hip_runtime.h>
#include <hip/hip_bf16.h>
#include <math.h>

// Tucker MoE: T=1024 tokens, D=1024, DFF=1024, R=64, G=8, E=32, NEXP=256, K=8
// F = T*K = 8192 routed (token, expert) pairs.
// Round 1: pure fp32 vector baseline (no MFMA; CDNA4 has no fp32 MFMA and the
// absmax threshold is strict enough that we establish fp32 correctness first).

#define T_ 1024
#define D_ 1024
#define DFF_ 1024
#define R_ 64
#define G_ 8
#define E_ 32
#define NEXP_ 256
#define K_ 8
#define F_ 8192

// ---------------------------------------------------------------- router GEMM
// logits[t][e] = sum_d x[t][d] * Wg[d][e].  4 tokens/block, thread = expert.
__global__ __launch_bounds__(256) void k_logits(const float* __restrict__ x,
                                                const float* __restrict__ Wg,
                                                float* __restrict__ logits) {
  __shared__ float xs[4][64];
  int t0 = blockIdx.x * 4;
  int e = threadIdx.x;
  float a0 = 0.f, a1 = 0.f, a2 = 0.f, a3 = 0.f;
  for (int dc = 0; dc < D_; dc += 64) {
    int tl = threadIdx.x >> 6, d = threadIdx.x & 63;
    xs[tl][d] = x[(t0 + tl) * D_ + dc + d];
    __syncthreads();
#pragma unroll 16
    for (int d2 = 0; d2 < 64; ++d2) {
      float wv = Wg[(size_t)(dc + d2) * NEXP_ + e];
      a0 = fmaf(xs[0][d2], wv, a0);
      a1 = fmaf(xs[1][d2], wv, a1);
      a2 = fmaf(xs[2][d2], wv, a2);
      a3 = fmaf(xs[3][d2], wv, a3);
    }
    __syncthreads();
  }
  logits[(size_t)(t0 + 0) * NEXP_ + e] = a0;
  logits[(size_t)(t0 + 1) * NEXP_ + e] = a1;
  logits[(size_t)(t0 + 2) * NEXP_ + e] = a2;
  logits[(size_t)(t0 + 3) * NEXP_ + e] = a3;
}

// ---------------------------------------------------------------- top-k + softmax
// One 64-lane wave per token. Iterative argmax extraction (8 rounds), ties ->
// lower index (jax.lax.top_k semantics). Softmax over the 8 selected logits.
__global__ __launch_bounds__(256) void k_topk(const float* __restrict__ logits,
                                              int* __restrict__ sel,
                                              float* __restrict__ wsm,
                                              int* __restrict__ cnt) {
  int wave = threadIdx.x >> 6;
  int lane = threadIdx.x & 63;
  int t = blockIdx.x * 4 + wave;

  float v[4];
  int idx[4];
#pragma unroll
  for (int j = 0; j < 4; ++j) {
    idx[j] = lane + 64 * j;
    v[j] = logits[(size_t)t * NEXP_ + idx[j]];
  }

  float topv[K_];
  int topi[K_];
#pragma unroll
  for (int k = 0; k < K_; ++k) {
    float bv = v[0];
    int bi = idx[0];
#pragma unroll
    for (int j = 1; j < 4; ++j)
      if (v[j] > bv || (v[j] == bv && idx[j] < bi)) { bv = v[j]; bi = idx[j]; }
    // butterfly: every lane converges to the global (max, min-index)
#pragma unroll
    for (int off = 32; off > 0; off >>= 1) {
      float ov = __shfl_xor(bv, off);
      int oi = __shfl_xor(bi, off);
      if (ov > bv || (ov == bv && oi < bi)) { bv = ov; bi = oi; }
    }
    topv[k] = bv;
    topi[k] = bi;
#pragma unroll
    for (int j = 0; j < 4; ++j)
      if (idx[j] == bi) v[j] = -INFINITY;
  }

  float m = topv[0];
  float ev[K_];
  float s = 0.f;
#pragma unroll
  for (int k = 0; k < K_; ++k) { ev[k] = expf(topv[k] - m); s += ev[k]; }
  float inv = 1.f / s;
  if (lane < K_) {
    sel[t * K_ + lane] = topi[lane];
    wsm[t * K_ + lane] = ev[lane] * inv;
    atomicAdd(&cnt[topi[lane]], 1);
  }
}

// ---------------------------------------------------------------- scan over 256 expert counts
__global__ __launch_bounds__(256) void k_scan(const int* __restrict__ cnt,
                                              int* __restrict__ off) {
  __shared__ int s[NEXP_];
  int i = threadIdx.x;
  s[i] = cnt[i];
  __syncthreads();
  for (int d = 1; d < NEXP_; d <<= 1) {
    int v = (i >= d) ? s[i - d] : 0;
    __syncthreads();
    s[i] += v;
    __syncthreads();
  }
  off[i + 1] = s[i];
  if (i == 0) off[0] = 0;
}

// ---------------------------------------------------------------- scatter pairs into expert-sorted order
__global__ __launch_bounds__(256) void k_scatter(const int* __restrict__ sel,
                                                 const float* __restrict__ wsm,
                                                 const int* __restrict__ off,
                                                 int* __restrict__ cur,
                                                 int* __restrict__ stok,
                                                 int* __restrict__ se,
                                                 float* __restrict__ sw,
                                                 int* __restrict__ ipos) {
  int f = blockIdx.x * 256 + threadIdx.x;  // f < F_
  int e = sel[f];
  int p = off[e] + atomicAdd(&cur[e], 1);
  stok[p] = f >> 3;
  se[p] = e;
  sw[p] = wsm[f];
  ipos[f] = p;
}

// ---------------------------------------------------------------- pre[g][t][r] = sum_d x[t][d]*uin[g][d][r]
// grid (T/64, G, 2{gate,up}); block 256; 64x64 out tile, 4x4 per thread.
__global__ __launch_bounds__(256) void k_pre(const float* __restrict__ x,
                                             const float* __restrict__ Ug,
                                             const float* __restrict__ Uu,
                                             float* __restrict__ Pg,
                                             float* __restrict__ Pu) {
  int g = blockIdx.y;
  const float* U = blockIdx.z ? Uu : Ug;
  float* P = blockIdx.z ? Pu : Pg;
  int t0 = blockIdx.x * 64;
  __shared__ float xs[64][65];
  __shared__ float us[64][65];
  int tx = threadIdx.x & 15, ty = threadIdx.x >> 4;
  float acc[4][4] = {};
  for (int dc = 0; dc < D_; dc += 64) {
    for (int i = threadIdx.x; i < 4096; i += 256) {
      int r = i >> 6, c = i & 63;
      xs[r][c] = x[(size_t)(t0 + r) * D_ + dc + c];
      us[r][c] = U[((size_t)g * D_ + dc + r) * R_ + c];
    }
    __syncthreads();
#pragma unroll 4
    for (int d = 0; d < 64; ++d) {
      float a[4], b[4];
#pragma unroll
      for (int i2 = 0; i2 < 4; ++i2) a[i2] = xs[ty * 4 + i2][d];
#pragma unroll
      for (int j = 0; j < 4; ++j) b[j] = us[d][tx * 4 + j];
#pragma unroll
      for (int i2 = 0; i2 < 4; ++i2)
#pragma unroll
        for (int j = 0; j < 4; ++j) acc[i2][j] = fmaf(a[i2], b[j], acc[i2][j]);
    }
    __syncthreads();
  }
#pragma unroll
  for (int i2 = 0; i2 < 4; ++i2) {
    float4 o4 = make_float4(acc[i2][0], acc[i2][1], acc[i2][2], acc[i2][3]);
    *(float4*)&P[((size_t)g * T_ + t0 + ty * 4 + i2) * R_ + tx * 4] = o4;
  }
}

// ---------------------------------------------------------------- per-pair Tucker core (gate+up)
// xg[p][o] = sum_r pre_g[g][tok][r] * core_g[e][r][o]; 4 pairs/block.
__global__ __launch_bounds__(256) void k_core_gu(const float* __restrict__ pre_g,
                                                 const float* __restrict__ pre_u,
                                                 const float* __restrict__ core_g,
                                                 const float* __restrict__ core_u,
                                                 const int* __restrict__ stok,
                                                 const int* __restrict__ se,
                                                 float* __restrict__ xg,
                                                 float* __restrict__ xu) {
  int pl = threadIdx.x >> 6;
  int o = threadIdx.x & 63;
  int p = blockIdx.x * 4 + pl;
  int e = se[p];
  int t = stok[p];
  int g = e >> 5;  // e / E_
  __shared__ float rg[4][64], ru[4][64];
  rg[pl][o] = pre_g[((size_t)g * T_ + t) * R_ + o];
  ru[pl][o] = pre_u[((size_t)g * T_ + t) * R_ + o];
  __syncthreads();
  const float* cg = core_g + (size_t)e * R_ * R_;
  const float* cu = core_u + (size_t)e * R_ * R_;
  float ag = 0.f, au = 0.f;
#pragma unroll 8
  for (int r = 0; r < R_; ++r) {
    ag = fmaf(rg[pl][r], cg[r * R_ + o], ag);
    au = fmaf(ru[pl][r], cu[r * R_ + o], au);
  }
  xg[(size_t)p * R_ + o] = ag;
  xu[(size_t)p * R_ + o] = au;
}

// ---------------------------------------------------------------- act = silu(xg@Uog) * (xu@Uou)
// grid (tiles, G, DFF/64); grid-stride over group tiles for any distribution.
__global__ __launch_bounds__(256) void k_act(const float* __restrict__ xg,
                                             const float* __restrict__ xu,
                                             const float* __restrict__ uout_g,
                                             const float* __restrict__ uout_u,
                                             const int* __restrict__ off,
                                             float* __restrict__ act) {
  int g = blockIdx.y;
  int p0 = off[g * E_];
  int pend = off[g * E_ + E_];
  int ntiles = (pend - p0 + 63) >> 6;
  int c0 = blockIdx.z * 64;
  int tx = threadIdx.x & 15, ty = threadIdx.x >> 4;
  __shared__ float ag[64][65], au[64][65], bg[64][65], bu[64][65];
  for (int tile = blockIdx.x; tile < ntiles; tile += gridDim.x) {
    int pbase = p0 + tile * 64;
    for (int i = threadIdx.x; i < 4096; i += 256) {
      int r = i >> 6, c = i & 63;
      bool ok = (pbase + r) < pend;
      ag[r][c] = ok ? xg[(size_t)(pbase + r) * R_ + c] : 0.f;
      au[r][c] = ok ? xu[(size_t)(pbase + r) * R_ + c] : 0.f;
      bg[r][c] = uout_g[((size_t)g * R_ + r) * DFF_ + c0 + c];
      bu[r][c] = uout_u[((size_t)g * R_ + r) * DFF_ + c0 + c];
    }
    __syncthreads();
    float accg[4][4] = {}, accu[4][4] = {};
#pragma unroll 4
    for (int r = 0; r < 64; ++r) {
      float a1[4], a2[4], b1[4], b2[4];
#pragma unroll
      for (int i2 = 0; i2 < 4; ++i2) { a1[i2] = ag[ty * 4 + i2][r]; a2[i2] = au[ty * 4 + i2][r]; }
#pragma unroll
      for (int j = 0; j < 4; ++j) { b1[j] = bg[r][tx * 4 + j]; b2[j] = bu[r][tx * 4 + j]; }
#pragma unroll
      for (int i2 = 0; i2 < 4; ++i2)
#pragma unroll
        for (int j = 0; j < 4; ++j) {
          accg[i2][j] = fmaf(a1[i2], b1[j], accg[i2][j]);
          accu[i2][j] = fmaf(a2[i2], b2[j], accu[i2][j]);
        }
    }
#pragma unroll
    for (int i2 = 0; i2 < 4; ++i2) {
      int p = pbase + ty * 4 + i2;
      if (p < pend) {
        float4 o4;
        float gv0 = accg[i2][0], gv1 = accg[i2][1], gv2 = accg[i2][2], gv3 = accg[i2][3];
        o4.x = gv0 / (1.f + expf(-gv0)) * accu[i2][0];
        o4.y = gv1 / (1.f + expf(-gv1)) * accu[i2][1];
        o4.z = gv2 / (1.f + expf(-gv2)) * accu[i2][2];
        o4.w = gv3 / (1.f + expf(-gv3)) * accu[i2][3];
        *(float4*)&act[(size_t)p * DFF_ + c0 + tx * 4] = o4;
      }
    }
    __syncthreads();
  }
}

// ---------------------------------------------------------------- xd = act@uin_down ; xd2 = xd@core_down[e]
__global__ __launch_bounds__(256) void k_down(const float* __restrict__ act,
                                              const float* __restrict__ uin_d,
                                              const float* __restrict__ core_d,
                                              const int* __restrict__ off,
                                              const int* __restrict__ se,
                                              float* __restrict__ xd2) {
  int g = blockIdx.y;
  int p0 = off[g * E_];
  int pend = off[g * E_ + E_];
  int ntiles = (pend - p0 + 63) >> 6;
  int tx = threadIdx.x & 15, ty = threadIdx.x >> 4;
  __shared__ float as[64][65], bs[64][65];
  for (int tile = blockIdx.x; tile < ntiles; tile += gridDim.x) {
    int pbase = p0 + tile * 64;
    float acc[4][4] = {};
    for (int cc = 0; cc < DFF_; cc += 64) {
      for (int i = threadIdx.x; i < 4096; i += 256) {
        int r = i >> 6, c = i & 63;
        as[r][c] = ((pbase + r) < pend) ? act[(size_t)(pbase + r) * DFF_ + cc + c] : 0.f;
        bs[r][c] = uin_d[((size_t)g * DFF_ + cc + r) * R_ + c];
      }
      __syncthreads();
#pragma unroll 4
      for (int r = 0; r < 64; ++r) {
        float a[4], b[4];
#pragma unroll
        for (int i2 = 0; i2 < 4; ++i2) a[i2] = as[ty * 4 + i2][r];
#pragma unroll
        for (int j = 0; j < 4; ++j) b[j] = bs[r][tx * 4 + j];
#pragma unroll
        for (int i2 = 0; i2 < 4; ++i2)
#pragma unroll
          for (int j = 0; j < 4; ++j) acc[i2][j] = fmaf(a[i2], b[j], acc[i2][j]);
      }
      __syncthreads();
    }
    // stash xin_d tile in LDS, then apply the per-pair 64x64 down core
#pragma unroll
    for (int i2 = 0; i2 < 4; ++i2)
#pragma unroll
      for (int j = 0; j < 4; ++j) as[ty * 4 + i2][tx * 4 + j] = acc[i2][j];
    __syncthreads();
    int o = threadIdx.x & 63;
    int sub = threadIdx.x >> 6;
    for (int pi = sub; pi < 64; pi += 4) {
      int p = pbase + pi;
      if (p < pend) {
        const float* cd = core_d + (size_t)se[p] * R_ * R_;
        float s = 0.f;
#pragma unroll 8
        for (int r = 0; r < R_; ++r) s = fmaf(as[pi][r], cd[r * R_ + o], s);
        xd2[(size_t)p * R_ + o] = s;
      }
    }
    __syncthreads();
  }
}

// ---------------------------------------------------------------- out_f = w[p] * (xd2 @ uout_down[g])
__global__ __launch_bounds__(256) void k_outf(const float* __restrict__ xd2,
                                              const float* __restrict__ uout_d,
                                              const int* __restrict__ off,
                                              const float* __restrict__ sw,
                                              float* __restrict__ outf) {
  int g = blockIdx.y;
  int p0 = off[g * E_];
  int pend = off[g * E_ + E_];
  int ntiles = (pend - p0 + 63) >> 6;
  int c0 = blockIdx.z * 64;
  int tx = threadIdx.x & 15, ty = threadIdx.x >> 4;
  __shared__ float as[64][65], bs[64][65];
  for (int tile = blockIdx.x; tile < ntiles; tile += gridDim.x) {
    int pbase = p0 + tile * 64;
    for (int i = threadIdx.x; i < 4096; i += 256) {
      int r = i >> 6, c = i & 63;
      as[r][c] = ((pbase + r) < pend) ? xd2[(size_t)(pbase + r) * R_ + c] : 0.f;
      bs[r][c] = uout_d[((size_t)g * R_ + r) * D_ + c0 + c];
    }
    __syncthreads();
    float acc[4][4] = {};
#pragma unroll 4
    for (int r = 0; r < 64; ++r) {
      float a[4], b[4];
#pragma unroll
      for (int i2 = 0; i2 < 4; ++i2) a[i2] = as[ty * 4 + i2][r];
#pragma unroll
      for (int j = 0; j < 4; ++j) b[j] = bs[r][tx * 4 + j];
#pragma unroll
      for (int i2 = 0; i2 < 4; ++i2)
#pragma unroll
        for (int j = 0; j < 4; ++j) acc[i2][j] = fmaf(a[i2], b[j], acc[i2][j]);
    }
#pragma unroll
    for (int i2 = 0; i2 < 4; ++i2) {
      int p = pbase + ty * 4 + i2;
      if (p < pend) {
        float wv = sw[p];
        float4 o4 = make_float4(acc[i2][0] * wv, acc[i2][1] * wv, acc[i2][2] * wv, acc[i2][3] * wv);
        *(float4*)&outf[(size_t)p * D_ + c0 + tx * 4] = o4;
      }
    }
    __syncthreads();
  }
}

// ---------------------------------------------------------------- gather: out[t] = sum_k outf[ipos[t*8+k]]
__global__ __launch_bounds__(256) void k_gather(const float* __restrict__ outf,
                                                const int* __restrict__ ipos,
                                                float* __restrict__ out) {
  int t = blockIdx.x;
  __shared__ int pos[K_];
  if (threadIdx.x < K_) pos[threadIdx.x] = ipos[t * K_ + threadIdx.x];
  __syncthreads();
  int c = threadIdx.x * 4;
  float4 s = make_float4(0.f, 0.f, 0.f, 0.f);
#pragma unroll
  for (int k = 0; k < K_; ++k) {
    float4 v = *(const float4*)(outf + (size_t)pos[k] * D_ + c);
    s.x += v.x; s.y += v.y; s.z += v.z; s.w += v.w;
  }
  *(float4*)(out + (size_t)t * D_ + c) = s;
}

// ================================================================ launch
extern "C" void kernel_launch(void* const* d_in, const int* in_sizes, int n_in,
                              void* d_out, int out_size, void* d_ws, size_t ws_size,
                              hipStream_t stream) {
  const float* x = (const float*)d_in[0];
  const float* Wg = (const float*)d_in[1];
  const float* uin_gate = (const float*)d_in[2];
  const float* core_gate = (const float*)d_in[3];
  const float* uout_gate = (const float*)d_in[4];
  const float* uin_up = (const float*)d_in[5];
  const float* core_up = (const float*)d_in[6];
  const float* uout_up = (const float*)d_in[7];
  const float* uin_down = (const float*)d_in[8];
  const float* core_down = (const float*)d_in[9];
  const float* uout_down = (const float*)d_in[10];
  float* out = (float*)d_out;

  char* ws = (char*)d_ws;
  size_t o = 0;
  auto alloc = [&](size_t bytes) { size_t r = o; o = (o + bytes + 255) & ~(size_t)255; return r; };
  size_t o_logits = alloc((size_t)T_ * NEXP_ * 4);
  size_t o_sel = alloc(F_ * 4);
  size_t o_wsm = alloc(F_ * 4);
  size_t o_cnt = alloc(NEXP_ * 4);
  size_t o_cur = alloc(NEXP_ * 4);
  size_t o_off = alloc((NEXP_ + 1) * 4);
  size_t o_stok = alloc(F_ * 4);
  size_t o_se = alloc(F_ * 4);
  size_t o_sw = alloc(F_ * 4);
  size_t o_ipos = alloc(F_ * 4);
  size_t o_pg = alloc((size_t)G_ * T_ * R_ * 4);
  size_t o_pu = alloc((size_t)G_ * T_ * R_ * 4);
  size_t o_xg = alloc((size_t)F_ * R_ * 4);
  size_t o_xu = alloc((size_t)F_ * R_ * 4);
  size_t o_xd2 = alloc((size_t)F_ * R_ * 4);
  size_t o_act = alloc((size_t)F_ * DFF_ * 4);  // 32 MB; reused as out_f after k_down
  (void)ws_size;

  float* logits = (float*)(ws + o_logits);
  int* sel = (int*)(ws + o_sel);
  float* wsm = (float*)(ws + o_wsm);
  int* cnt = (int*)(ws + o_cnt);
  int* cur = (int*)(ws + o_cur);
  int* off = (int*)(ws + o_off);
  int* stok = (int*)(ws + o_stok);
  int* se = (int*)(ws + o_se);
  float* sw = (float*)(ws + o_sw);
  int* ipos = (int*)(ws + o_ipos);
  float* pg = (float*)(ws + o_pg);
  float* pu = (float*)(ws + o_pu);
  float* xg = (float*)(ws + o_xg);
  float* xu = (float*)(ws + o_xu);
  float* xd2 = (float*)(ws + o_xd2);
  float* act = (float*)(ws + o_act);
  float* outf = act;  // alias: act is dead after k_down

  hipMemsetAsync(cnt, 0, NEXP_ * 4, stream);
  hipMemsetAsync(cur, 0, NEXP_ * 4, stream);

  k_logits<<<T_ / 4, 256, 0, stream>>>(x, Wg, logits);
  k_topk<<<T_ / 4, 256, 0, stream>>>(logits, sel, wsm, cnt);
  k_scan<<<1, 256, 0, stream>>>(cnt, off);
  k_scatter<<<F_ / 256, 256, 0, stream>>>(sel, wsm, off, cur, stok, se, sw, ipos);
  k_pre<<<dim3(T_ / 64, G_, 2), 256, 0, stream>>>(x, uin_gate, uin_up, pg, pu);
  k_core_gu<<<F_ / 4, 256, 0, stream>>>(pg, pu, core_gate, core_up, stok, se, xg, xu);
  k_act<<<dim3(16, G_, DFF_ / 64), 256, 0, stream>>>(xg, xu, uout_gate, uout_up, off, act);
  k_down<<<dim3(16, G_), 256, 0, stream>>>(act, uin_down, core_down, off, se, xd2);
  k_outf<<<dim3(16, G_, D_ / 64), 256, 0, stream>>>(xd2, uout_down, off, sw, outf);
  k_gather<<<T_, 256, 0, stream>>>(outf, ipos, out);
}

// Round 2
// 412.683 us; speedup vs baseline: 1.6299x; 1.6299x over previous
//
#include <hip/hip_runtime.h>
#include <hip/hip_bf16.h>
#include <math.h>

// Tucker MoE: T=1024 tokens, D=1024, DFF=1024, R=64, G=8, E=32, NEXP=256, K=8
// F = T*K = 8192 routed (token, expert) pairs.
// Round 2: split-K for the three latency-bound kernels (k_logits, k_pre,
// k_down) via deterministic partial buffers folded by the consumer.
// R1 counters: k_down 285us @ 3.4% occupancy / 3.9% VALUBusy (128 blocks,
// K=1024 serial loop) -- pure latency exposure, fixed by 8x more blocks.

#define T_ 1024
#define D_ 1024
#define DFF_ 1024
#define R_ 64
#define G_ 8
#define E_ 32
#define NEXP_ 256
#define K_ 8
#define F_ 8192
#define LKZ_ 4   // k_logits split-K
#define PKZ_ 4   // k_pre split-K
#define DKZ_ 8   // k_down split-K

// ---------------------------------------------------------------- router GEMM (split-K)
// lp[z][t][e] = sum_{d in chunk z} x[t][d] * Wg[d][e].  4 tokens/block.
__global__ __launch_bounds__(256) void k_logits(const float* __restrict__ x,
                                                const float* __restrict__ Wg,
                                                float* __restrict__ lp) {
  __shared__ float xs[4][64];
  int t0 = blockIdx.x * 4;
  int z = blockIdx.y;
  int e = threadIdx.x;
  float a0 = 0.f, a1 = 0.f, a2 = 0.f, a3 = 0.f;
  int dlo = z * (D_ / LKZ_), dhi = dlo + D_ / LKZ_;
  for (int dc = dlo; dc < dhi; dc += 64) {
    int tl = threadIdx.x >> 6, d = threadIdx.x & 63;
    xs[tl][d] = x[(t0 + tl) * D_ + dc + d];
    __syncthreads();
#pragma unroll 16
    for (int d2 = 0; d2 < 64; ++d2) {
      float wv = Wg[(size_t)(dc + d2) * NEXP_ + e];
      a0 = fmaf(xs[0][d2], wv, a0);
      a1 = fmaf(xs[1][d2], wv, a1);
      a2 = fmaf(xs[2][d2], wv, a2);
      a3 = fmaf(xs[3][d2], wv, a3);
    }
    __syncthreads();
  }
  size_t base = (size_t)z * T_ * NEXP_;
  lp[base + (size_t)(t0 + 0) * NEXP_ + e] = a0;
  lp[base + (size_t)(t0 + 1) * NEXP_ + e] = a1;
  lp[base + (size_t)(t0 + 2) * NEXP_ + e] = a2;
  lp[base + (size_t)(t0 + 3) * NEXP_ + e] = a3;
}

// ---------------------------------------------------------------- top-k + softmax
// One 64-lane wave per token; folds the LKZ_ logits partials on load.
__global__ __launch_bounds__(256) void k_topk(const float* __restrict__ lp,
                                              int* __restrict__ sel,
                                              float* __restrict__ wsm,
                                              int* __restrict__ cnt) {
  int wave = threadIdx.x >> 6;
  int lane = threadIdx.x & 63;
  int t = blockIdx.x * 4 + wave;

  float v[4];
  int idx[4];
#pragma unroll
  for (int j = 0; j < 4; ++j) {
    idx[j] = lane + 64 * j;
    float s = 0.f;
#pragma unroll
    for (int z = 0; z < LKZ_; ++z)
      s += lp[(size_t)z * T_ * NEXP_ + (size_t)t * NEXP_ + idx[j]];
    v[j] = s;
  }

  float topv[K_];
  int topi[K_];
#pragma unroll
  for (int k = 0; k < K_; ++k) {
    float bv = v[0];
    int bi = idx[0];
#pragma unroll
    for (int j = 1; j < 4; ++j)
      if (v[j] > bv || (v[j] == bv && idx[j] < bi)) { bv = v[j]; bi = idx[j]; }
#pragma unroll
    for (int off = 32; off > 0; off >>= 1) {
      float ov = __shfl_xor(bv, off);
      int oi = __shfl_xor(bi, off);
      if (ov > bv || (ov == bv && oi < bi)) { bv = ov; bi = oi; }
    }
    topv[k] = bv;
    topi[k] = bi;
#pragma unroll
    for (int j = 0; j < 4; ++j)
      if (idx[j] == bi) v[j] = -INFINITY;
  }

  float m = topv[0];
  float ev[K_];
  float s = 0.f;
#pragma unroll
  for (int k = 0; k < K_; ++k) { ev[k] = expf(topv[k] - m); s += ev[k]; }
  float inv = 1.f / s;
  if (lane < K_) {
    sel[t * K_ + lane] = topi[lane];
    wsm[t * K_ + lane] = ev[lane] * inv;
    atomicAdd(&cnt[topi[lane]], 1);
  }
}

// ---------------------------------------------------------------- scan over 256 expert counts
__global__ __launch_bounds__(256) void k_scan(const int* __restrict__ cnt,
                                              int* __restrict__ off) {
  __shared__ int s[NEXP_];
  int i = threadIdx.x;
  s[i] = cnt[i];
  __syncthreads();
  for (int d = 1; d < NEXP_; d <<= 1) {
    int v = (i >= d) ? s[i - d] : 0;
    __syncthreads();
    s[i] += v;
    __syncthreads();
  }
  off[i + 1] = s[i];
  if (i == 0) off[0] = 0;
}

// ---------------------------------------------------------------- scatter pairs into expert-sorted order
__global__ __launch_bounds__(256) void k_scatter(const int* __restrict__ sel,
                                                 const float* __restrict__ wsm,
                                                 const int* __restrict__ off,
                                                 int* __restrict__ cur,
                                                 int* __restrict__ stok,
                                                 int* __restrict__ se,
                                                 float* __restrict__ sw,
                                                 int* __restrict__ ipos) {
  int f = blockIdx.x * 256 + threadIdx.x;  // f < F_
  int e = sel[f];
  int p = off[e] + atomicAdd(&cur[e], 1);
  stok[p] = f >> 3;
  se[p] = e;
  sw[p] = wsm[f];
  ipos[f] = p;
}

// ---------------------------------------------------------------- pre partials (split-K)
// Pp[kz][g][t][r] += x[t][dchunk] * uin[g][dchunk][r].
// grid (T/64, G, 2*PKZ_); z = gu*PKZ_ + kz.
__global__ __launch_bounds__(256) void k_pre(const float* __restrict__ x,
                                             const float* __restrict__ Ug,
                                             const float* __restrict__ Uu,
                                             float* __restrict__ Pgp,
                                             float* __restrict__ Pup) {
  int g = blockIdx.y;
  int gu = blockIdx.z / PKZ_;
  int kz = blockIdx.z % PKZ_;
  const float* U = gu ? Uu : Ug;
  float* P = gu ? Pup : Pgp;
  int t0 = blockIdx.x * 64;
  __shared__ float xs[64][65];
  __shared__ float us[64][65];
  int tx = threadIdx.x & 15, ty = threadIdx.x >> 4;
  float acc[4][4] = {};
  int dlo = kz * (D_ / PKZ_), dhi = dlo + D_ / PKZ_;
  for (int dc = dlo; dc < dhi; dc += 64) {
    for (int i = threadIdx.x; i < 4096; i += 256) {
      int r = i >> 6, c = i & 63;
      xs[r][c] = x[(size_t)(t0 + r) * D_ + dc + c];
      us[r][c] = U[((size_t)g * D_ + dc + r) * R_ + c];
    }
    __syncthreads();
#pragma unroll 4
    for (int d = 0; d < 64; ++d) {
      float a[4], b[4];
#pragma unroll
      for (int i2 = 0; i2 < 4; ++i2) a[i2] = xs[ty * 4 + i2][d];
#pragma unroll
      for (int j = 0; j < 4; ++j) b[j] = us[d][tx * 4 + j];
#pragma unroll
      for (int i2 = 0; i2 < 4; ++i2)
#pragma unroll
        for (int j = 0; j < 4; ++j) acc[i2][j] = fmaf(a[i2], b[j], acc[i2][j]);
    }
    __syncthreads();
  }
#pragma unroll
  for (int i2 = 0; i2 < 4; ++i2) {
    float4 o4 = make_float4(acc[i2][0], acc[i2][1], acc[i2][2], acc[i2][3]);
    *(float4*)&P[((size_t)(kz * G_ + g) * T_ + t0 + ty * 4 + i2) * R_ + tx * 4] = o4;
  }
}

// ---------------------------------------------------------------- per-pair Tucker core (gate+up)
// Folds PKZ_ pre-partials, then xg[p][o] = sum_r pre[r] * core[e][r][o]; 4 pairs/block.
__global__ __launch_bounds__(256) void k_core_gu(const float* __restrict__ Pgp,
                                                 const float* __restrict__ Pup,
                                                 const float* __restrict__ core_g,
                                                 const float* __restrict__ core_u,
                                                 const int* __restrict__ stok,
                                                 const int* __restrict__ se,
                                                 float* __restrict__ xg,
                                                 float* __restrict__ xu) {
  int pl = threadIdx.x >> 6;
  int o = threadIdx.x & 63;
  int p = blockIdx.x * 4 + pl;
  int e = se[p];
  int t = stok[p];
  int g = e >> 5;
  __shared__ float rg[4][64], ru[4][64];
  float sg = 0.f, su = 0.f;
#pragma unroll
  for (int kz = 0; kz < PKZ_; ++kz) {
    sg += Pgp[((size_t)(kz * G_ + g) * T_ + t) * R_ + o];
    su += Pup[((size_t)(kz * G_ + g) * T_ + t) * R_ + o];
  }
  rg[pl][o] = sg;
  ru[pl][o] = su;
  __syncthreads();
  const float* cg = core_g + (size_t)e * R_ * R_;
  const float* cu = core_u + (size_t)e * R_ * R_;
  float ag = 0.f, au = 0.f;
#pragma unroll 8
  for (int r = 0; r < R_; ++r) {
    ag = fmaf(rg[pl][r], cg[r * R_ + o], ag);
    au = fmaf(ru[pl][r], cu[r * R_ + o], au);
  }
  xg[(size_t)p * R_ + o] = ag;
  xu[(size_t)p * R_ + o] = au;
}

// ---------------------------------------------------------------- act = silu(xg@Uog) * (xu@Uou)
__global__ __launch_bounds__(256) void k_act(const float* __restrict__ xg,
                                             const float* __restrict__ xu,
                                             const float* __restrict__ uout_g,
                                             const float* __restrict__ uout_u,
                                             const int* __restrict__ off,
                                             float* __restrict__ act) {
  int g = blockIdx.y;
  int p0 = off[g * E_];
  int pend = off[g * E_ + E_];
  int ntiles = (pend - p0 + 63) >> 6;
  int c0 = blockIdx.z * 64;
  int tx = threadIdx.x & 15, ty = threadIdx.x >> 4;
  __shared__ float ag[64][65], au[64][65], bg[64][65], bu[64][65];
  for (int tile = blockIdx.x; tile < ntiles; tile += gridDim.x) {
    int pbase = p0 + tile * 64;
    for (int i = threadIdx.x; i < 4096; i += 256) {
      int r = i >> 6, c = i & 63;
      bool ok = (pbase + r) < pend;
      ag[r][c] = ok ? xg[(size_t)(pbase + r) * R_ + c] : 0.f;
      au[r][c] = ok ? xu[(size_t)(pbase + r) * R_ + c] : 0.f;
      bg[r][c] = uout_g[((size_t)g * R_ + r) * DFF_ + c0 + c];
      bu[r][c] = uout_u[((size_t)g * R_ + r) * DFF_ + c0 + c];
    }
    __syncthreads();
    float accg[4][4] = {}, accu[4][4] = {};
#pragma unroll 4
    for (int r = 0; r < 64; ++r) {
      float a1[4], a2[4], b1[4], b2[4];
#pragma unroll
      for (int i2 = 0; i2 < 4; ++i2) { a1[i2] = ag[ty * 4 + i2][r]; a2[i2] = au[ty * 4 + i2][r]; }
#pragma unroll
      for (int j = 0; j < 4; ++j) { b1[j] = bg[r][tx * 4 + j]; b2[j] = bu[r][tx * 4 + j]; }
#pragma unroll
      for (int i2 = 0; i2 < 4; ++i2)
#pragma unroll
        for (int j = 0; j < 4; ++j) {
          accg[i2][j] = fmaf(a1[i2], b1[j], accg[i2][j]);
          accu[i2][j] = fmaf(a2[i2], b2[j], accu[i2][j]);
        }
    }
#pragma unroll
    for (int i2 = 0; i2 < 4; ++i2) {
      int p = pbase + ty * 4 + i2;
      if (p < pend) {
        float4 o4;
        float gv0 = accg[i2][0], gv1 = accg[i2][1], gv2 = accg[i2][2], gv3 = accg[i2][3];
        o4.x = gv0 / (1.f + expf(-gv0)) * accu[i2][0];
        o4.y = gv1 / (1.f + expf(-gv1)) * accu[i2][1];
        o4.z = gv2 / (1.f + expf(-gv2)) * accu[i2][2];
        o4.w = gv3 / (1.f + expf(-gv3)) * accu[i2][3];
        *(float4*)&act[(size_t)p * DFF_ + c0 + tx * 4] = o4;
      }
    }
    __syncthreads();
  }
}

// ---------------------------------------------------------------- xd partials (split-K over DFF)
// xdp[kz][p][r] = act[p][chunk] @ uin_down[g][chunk][r].  grid (16, G, DKZ_).
__global__ __launch_bounds__(256) void k_downA(const float* __restrict__ act,
                                               const float* __restrict__ uin_d,
                                               const int* __restrict__ off,
                                               float* __restrict__ xdp) {
  int g = blockIdx.y;
  int kz = blockIdx.z;
  int p0 = off[g * E_];
  int pend = off[g * E_ + E_];
  int ntiles = (pend - p0 + 63) >> 6;
  int tx = threadIdx.x & 15, ty = threadIdx.x >> 4;
  __shared__ float as[64][65], bs[64][65];
  int clo = kz * (DFF_ / DKZ_), chi = clo + DFF_ / DKZ_;
  for (int tile = blockIdx.x; tile < ntiles; tile += gridDim.x) {
    int pbase = p0 + tile * 64;
    float acc[4][4] = {};
    for (int cc = clo; cc < chi; cc += 64) {
      for (int i = threadIdx.x; i < 4096; i += 256) {
        int r = i >> 6, c = i & 63;
        as[r][c] = ((pbase + r) < pend) ? act[(size_t)(pbase + r) * DFF_ + cc + c] : 0.f;
        bs[r][c] = uin_d[((size_t)g * DFF_ + cc + r) * R_ + c];
      }
      __syncthreads();
#pragma unroll 4
      for (int r = 0; r < 64; ++r) {
        float a[4], b[4];
#pragma unroll
        for (int i2 = 0; i2 < 4; ++i2) a[i2] = as[ty * 4 + i2][r];
#pragma unroll
        for (int j = 0; j < 4; ++j) b[j] = bs[r][tx * 4 + j];
#pragma unroll
        for (int i2 = 0; i2 < 4; ++i2)
#pragma unroll
          for (int j = 0; j < 4; ++j) acc[i2][j] = fmaf(a[i2], b[j], acc[i2][j]);
      }
      __syncthreads();
    }
#pragma unroll
    for (int i2 = 0; i2 < 4; ++i2) {
      int p = pbase + ty * 4 + i2;
      if (p < pend) {
        float4 o4 = make_float4(acc[i2][0], acc[i2][1], acc[i2][2], acc[i2][3]);
        *(float4*)&xdp[((size_t)kz * F_ + p) * R_ + tx * 4] = o4;
      }
    }
  }
}

// ---------------------------------------------------------------- fold xd partials + per-pair down core
__global__ __launch_bounds__(256) void k_core_down(const float* __restrict__ xdp,
                                                   const float* __restrict__ core_d,
                                                   const int* __restrict__ se,
                                                   float* __restrict__ xd2) {
  int pl = threadIdx.x >> 6;
  int o = threadIdx.x & 63;
  int p = blockIdx.x * 4 + pl;
  int e = se[p];
  __shared__ float rg[4][64];
  float s = 0.f;
#pragma unroll
  for (int kz = 0; kz < DKZ_; ++kz) s += xdp[((size_t)kz * F_ + p) * R_ + o];
  rg[pl][o] = s;
  __syncthreads();
  const float* cd = core_d + (size_t)e * R_ * R_;
  float a = 0.f;
#pragma unroll 8
  for (int r = 0; r < R_; ++r) a = fmaf(rg[pl][r], cd[r * R_ + o], a);
  xd2[(size_t)p * R_ + o] = a;
}

// ---------------------------------------------------------------- out_f = w[p] * (xd2 @ uout_down[g])
__global__ __launch_bounds__(256) void k_outf(const float* __restrict__ xd2,
                                              const float* __restrict__ uout_d,
                                              const int* __restrict__ off,
                                              const float* __restrict__ sw,
                                              float* __restrict__ outf) {
  int g = blockIdx.y;
  int p0 = off[g * E_];
  int pend = off[g * E_ + E_];
  int ntiles = (pend - p0 + 63) >> 6;
  int c0 = blockIdx.z * 64;
  int tx = threadIdx.x & 15, ty = threadIdx.x >> 4;
  __shared__ float as[64][65], bs[64][65];
  for (int tile = blockIdx.x; tile < ntiles; tile += gridDim.x) {
    int pbase = p0 + tile * 64;
    for (int i = threadIdx.x; i < 4096; i += 256) {
      int r = i >> 6, c = i & 63;
      as[r][c] = ((pbase + r) < pend) ? xd2[(size_t)(pbase + r) * R_ + c] : 0.f;
      bs[r][c] = uout_d[((size_t)g * R_ + r) * D_ + c0 + c];
    }
    __syncthreads();
    float acc[4][4] = {};
#pragma unroll 4
    for (int r = 0; r < 64; ++r) {
      float a[4], b[4];
#pragma unroll
      for (int i2 = 0; i2 < 4; ++i2) a[i2] = as[ty * 4 + i2][r];
#pragma unroll
      for (int j = 0; j < 4; ++j) b[j] = bs[r][tx * 4 + j];
#pragma unroll
      for (int i2 = 0; i2 < 4; ++i2)
#pragma unroll
        for (int j = 0; j < 4; ++j) acc[i2][j] = fmaf(a[i2], b[j], acc[i2][j]);
    }
#pragma unroll
    for (int i2 = 0; i2 < 4; ++i2) {
      int p = pbase + ty * 4 + i2;
      if (p < pend) {
        float wv = sw[p];
        float4 o4 = make_float4(acc[i2][0] * wv, acc[i2][1] * wv, acc[i2][2] * wv, acc[i2][3] * wv);
        *(float4*)&outf[(size_t)p * D_ + c0 + tx * 4] = o4;
      }
    }
    __syncthreads();
  }
}

// ---------------------------------------------------------------- gather: out[t] = sum_k outf[ipos[t*8+k]]
__global__ __launch_bounds__(256) void k_gather(const float* __restrict__ outf,
                                                const int* __restrict__ ipos,
                                                float* __restrict__ out) {
  int t = blockIdx.x;
  __shared__ int pos[K_];
  if (threadIdx.x < K_) pos[threadIdx.x] = ipos[t * K_ + threadIdx.x];
  __syncthreads();
  int c = threadIdx.x * 4;
  float4 s = make_float4(0.f, 0.f, 0.f, 0.f);
#pragma unroll
  for (int k = 0; k < K_; ++k) {
    float4 v = *(const float4*)(outf + (size_t)pos[k] * D_ + c);
    s.x += v.x; s.y += v.y; s.z += v.z; s.w += v.w;
  }
  *(float4*)(out + (size_t)t * D_ + c) = s;
}

// ================================================================ launch
extern "C" void kernel_launch(void* const* d_in, const int* in_sizes, int n_in,
                              void* d_out, int out_size, void* d_ws, size_t ws_size,
                              hipStream_t stream) {
  const float* x = (const float*)d_in[0];
  const float* Wg = (const float*)d_in[1];
  const float* uin_gate = (const float*)d_in[2];
  const float* core_gate = (const float*)d_in[3];
  const float* uout_gate = (const float*)d_in[4];
  const float* uin_up = (const float*)d_in[5];
  const float* core_up = (const float*)d_in[6];
  const float* uout_up = (const float*)d_in[7];
  const float* uin_down = (const float*)d_in[8];
  const float* core_down = (const float*)d_in[9];
  const float* uout_down = (const float*)d_in[10];
  float* out = (float*)d_out;

  char* ws = (char*)d_ws;
  size_t o = 0;
  auto alloc = [&](size_t bytes) { size_t r = o; o = (o + bytes + 255) & ~(size_t)255; return r; };
  size_t o_lp = alloc((size_t)LKZ_ * T_ * NEXP_ * 4);      // 4 MB
  size_t o_sel = alloc(F_ * 4);
  size_t o_wsm = alloc(F_ * 4);
  size_t o_cnt = alloc(NEXP_ * 4);
  size_t o_cur = alloc(NEXP_ * 4);
  size_t o_off = alloc((NEXP_ + 1) * 4);
  size_t o_stok = alloc(F_ * 4);
  size_t o_se = alloc(F_ * 4);
  size_t o_sw = alloc(F_ * 4);
  size_t o_ipos = alloc(F_ * 4);
  size_t o_pgp = alloc((size_t)PKZ_ * G_ * T_ * R_ * 4);   // 8 MB
  size_t o_pup = alloc((size_t)PKZ_ * G_ * T_ * R_ * 4);   // 8 MB
  size_t o_xg = alloc((size_t)F_ * R_ * 4);
  size_t o_xu = alloc((size_t)F_ * R_ * 4);
  size_t o_xdp = alloc((size_t)DKZ_ * F_ * R_ * 4);        // 16 MB
  size_t o_xd2 = alloc((size_t)F_ * R_ * 4);
  size_t o_act = alloc((size_t)F_ * DFF_ * 4);             // 32 MB; reused as out_f
  (void)ws_size;

  float* lp = (float*)(ws + o_lp);
  int* sel = (int*)(ws + o_sel);
  float* wsm = (float*)(ws + o_wsm);
  int* cnt = (int*)(ws + o_cnt);
  int* cur = (int*)(ws + o_cur);
  int* off = (int*)(ws + o_off);
  int* stok = (int*)(ws + o_stok);
  int* se = (int*)(ws + o_se);
  float* sw = (float*)(ws + o_sw);
  int* ipos = (int*)(ws + o_ipos);
  float* pgp = (float*)(ws + o_pgp);
  float* pup = (float*)(ws + o_pup);
  float* xg = (float*)(ws + o_xg);
  float* xu = (float*)(ws + o_xu);
  float* xdp = (float*)(ws + o_xdp);
  float* xd2 = (float*)(ws + o_xd2);
  float* act = (float*)(ws + o_act);
  float* outf = act;  // alias: act is dead after k_downA

  hipMemsetAsync(cnt, 0, NEXP_ * 4, stream);
  hipMemsetAsync(cur, 0, NEXP_ * 4, stream);

  k_logits<<<dim3(T_ / 4, LKZ_), 256, 0, stream>>>(x, Wg, lp);
  k_topk<<<T_ / 4, 256, 0, stream>>>(lp, sel, wsm, cnt);
  k_scan<<<1, 256, 0, stream>>>(cnt, off);
  k_scatter<<<F_ / 256, 256, 0, stream>>>(sel, wsm, off, cur, stok, se, sw, ipos);
  k_pre<<<dim3(T_ / 64, G_, 2 * PKZ_), 256, 0, stream>>>(x, uin_gate, uin_up, pgp, pup);
  k_core_gu<<<F_ / 4, 256, 0, stream>>>(pgp, pup, core_gate, core_up, stok, se, xg, xu);
  k_act<<<dim3(16, G_, DFF_ / 64), 256, 0, stream>>>(xg, xu, uout_gate, uout_up, off, act);
  k_downA<<<dim3(16, G_, DKZ_), 256, 0, stream>>>(act, uin_down, off, xdp);
  k_core_down<<<F_ / 4, 256, 0, stream>>>(xdp, core_down, se, xd2);
  k_outf<<<dim3(16, G_, D_ / 64), 256, 0, stream>>>(xd2, uout_down, off, sw, outf);
  k_gather<<<T_, 256, 0, stream>>>(outf, ipos, out);
}

// Round 3
// 231.505 us; speedup vs baseline: 2.9055x; 1.7826x over previous
//
#include <hip/hip_runtime.h>
#include <hip/hip_bf16.h>
#include <math.h>

// Tucker MoE: T=1024, D=1024, DFF=1024, R=64, G=8, E=32, NEXP=256, K=8, F=8192
// Round 3: bf16 MFMA (16x16x32, fp32 acc) for the five GEMM-shaped kernels
// (pre, act-gate, act-up, down, outf). Router + core matvecs stay fp32.
// Weights are cast+transposed once per launch so A and B fragments both read
// k-contiguous ds_read_b128 from LDS (pitch 72 bf16 = 144 B rows, 2-way bank
// aliasing = free per m136).

#define T_ 1024
#define D_ 1024
#define DFF_ 1024
#define R_ 64
#define G_ 8
#define E_ 32
#define NEXP_ 256
#define K_ 8
#define F_ 8192
#define LKZ_ 4   // k_logits split-K
#define PKZ_ 2   // k_pre split-K
#define DKZ_ 4   // k_down split-K
#define LP_ 72   // LDS tile pitch in bf16 elems (16B-aligned rows)

typedef short bf16x8 __attribute__((ext_vector_type(8)));
typedef float f32x4 __attribute__((ext_vector_type(4)));

__device__ __forceinline__ unsigned short f2bf(float f) {
  unsigned int u = __float_as_uint(f);
  u += 0x7fffu + ((u >> 16) & 1u);  // RNE (inputs are finite)
  return (unsigned short)(u >> 16);
}

// Stage a 64x64 bf16 tile (global row-major, pitch gp elems) into LDS pitch-72.
__device__ __forceinline__ void stage_tile(short* dst, const unsigned short* src,
                                           int gp, int tid) {
  for (int idx = tid; idx < 512; idx += 256) {
    int r = idx >> 3, c8 = (idx & 7) << 3;
    *(uint4*)&dst[r * LP_ + c8] = *(const uint4*)&src[(size_t)r * gp + c8];
  }
}

__device__ __forceinline__ void stage_tile_guard(short* dst, const unsigned short* src,
                                                 int gp, int rows_valid, int tid) {
  for (int idx = tid; idx < 512; idx += 256) {
    int r = idx >> 3, c8 = (idx & 7) << 3;
    uint4 v = make_uint4(0u, 0u, 0u, 0u);
    if (r < rows_valid) v = *(const uint4*)&src[(size_t)r * gp + c8];
    *(uint4*)&dst[r * LP_ + c8] = v;
  }
}

// Wave computes a 16x64 strip (rows [ms,ms+16), all 64 cols) over K=64 from
// LDS tiles As (rows=m, k-contig) and Bs (rows=n, k-contig; i.e. B^T).
__device__ __forceinline__ void mma_strip(const short* As, const short* Bs,
                                          int ms, int lane, f32x4* acc) {
  int lm = lane & 15;
  int lk = (lane >> 4) << 3;
#pragma unroll
  for (int kc = 0; kc < 64; kc += 32) {
    bf16x8 a = *(const bf16x8*)&As[(ms + lm) * LP_ + kc + lk];
#pragma unroll
    for (int nt = 0; nt < 4; ++nt) {
      bf16x8 b = *(const bf16x8*)&Bs[(nt * 16 + lm) * LP_ + kc + lk];
      acc[nt] = __builtin_amdgcn_mfma_f32_16x16x32_bf16(a, b, acc[nt], 0, 0, 0);
    }
  }
}

// ---------------------------------------------------------------- casts
__global__ __launch_bounds__(256) void k_cast_x(const float* __restrict__ x,
                                                unsigned short* __restrict__ xb) {
  int i = (blockIdx.x * 256 + threadIdx.x) * 4;
  float4 v = *(const float4*)&x[i];
  xb[i + 0] = f2bf(v.x);
  xb[i + 1] = f2bf(v.y);
  xb[i + 2] = f2bf(v.z);
  xb[i + 3] = f2bf(v.w);
}

// Cast + transpose the six group-weight tensors to bf16.
// ids 0..2 (uin_gate, uin_up, uin_down): src [g][1024][64] -> dst [g][64][1024]
// ids 3..5 (uout_gate, uout_up, uout_down): src [g][64][1024] -> dst [g][1024][64]
__global__ __launch_bounds__(256) void k_castT(const float* __restrict__ s0, const float* __restrict__ s1,
                                               const float* __restrict__ s2, const float* __restrict__ s3,
                                               const float* __restrict__ s4, const float* __restrict__ s5,
                                               unsigned short* __restrict__ d0, unsigned short* __restrict__ d1,
                                               unsigned short* __restrict__ d2, unsigned short* __restrict__ d3,
                                               unsigned short* __restrict__ d4, unsigned short* __restrict__ d5) {
  __shared__ float ts[64][65];
  int id = blockIdx.z, g = blockIdx.y, tile = blockIdx.x;
  const float* src = id == 0 ? s0 : id == 1 ? s1 : id == 2 ? s2 : id == 3 ? s3 : id == 4 ? s4 : s5;
  unsigned short* dst = id == 0 ? d0 : id == 1 ? d1 : id == 2 ? d2 : id == 3 ? d3 : id == 4 ? d4 : d5;
  if (id < 3) {
    // src rows r0..r0+63 (of 1024), 64 cols
    int r0 = tile * 64;
    for (int idx = threadIdx.x; idx < 4096; idx += 256) {
      int r = idx >> 6, c = idx & 63;
      ts[r][c] = src[((size_t)g * 1024 + r0 + r) * 64 + c];
    }
    __syncthreads();
    for (int idx = threadIdx.x; idx < 4096; idx += 256) {
      int c = idx >> 6, r = idx & 63;
      dst[((size_t)g * 64 + c) * 1024 + r0 + r] = f2bf(ts[r][c]);
    }
  } else {
    // src 64 rows, cols c0..c0+63 (of 1024)
    int c0 = tile * 64;
    for (int idx = threadIdx.x; idx < 4096; idx += 256) {
      int r = idx >> 6, c = idx & 63;
      ts[r][c] = src[((size_t)g * 64 + r) * 1024 + c0 + c];
    }
    __syncthreads();
    for (int idx = threadIdx.x; idx < 4096; idx += 256) {
      int c = idx >> 6, r = idx & 63;
      dst[((size_t)g * 1024 + c0 + c) * 64 + r] = f2bf(ts[r][c]);
    }
  }
}

// ---------------------------------------------------------------- router GEMM (fp32, split-K)
__global__ __launch_bounds__(256) void k_logits(const float* __restrict__ x,
                                                const float* __restrict__ Wg,
                                                float* __restrict__ lp) {
  __shared__ float xs[4][64];
  int t0 = blockIdx.x * 4;
  int z = blockIdx.y;
  int e = threadIdx.x;
  float a0 = 0.f, a1 = 0.f, a2 = 0.f, a3 = 0.f;
  int dlo = z * (D_ / LKZ_), dhi = dlo + D_ / LKZ_;
  for (int dc = dlo; dc < dhi; dc += 64) {
    int tl = threadIdx.x >> 6, d = threadIdx.x & 63;
    xs[tl][d] = x[(t0 + tl) * D_ + dc + d];
    __syncthreads();
#pragma unroll 16
    for (int d2 = 0; d2 < 64; ++d2) {
      float wv = Wg[(size_t)(dc + d2) * NEXP_ + e];
      a0 = fmaf(xs[0][d2], wv, a0);
      a1 = fmaf(xs[1][d2], wv, a1);
      a2 = fmaf(xs[2][d2], wv, a2);
      a3 = fmaf(xs[3][d2], wv, a3);
    }
    __syncthreads();
  }
  size_t base = (size_t)z * T_ * NEXP_;
  lp[base + (size_t)(t0 + 0) * NEXP_ + e] = a0;
  lp[base + (size_t)(t0 + 1) * NEXP_ + e] = a1;
  lp[base + (size_t)(t0 + 2) * NEXP_ + e] = a2;
  lp[base + (size_t)(t0 + 3) * NEXP_ + e] = a3;
}

// ---------------------------------------------------------------- top-k + softmax (fp32)
__global__ __launch_bounds__(256) void k_topk(const float* __restrict__ lp,
                                              int* __restrict__ sel,
                                              float* __restrict__ wsm,
                                              int* __restrict__ cnt) {
  int wave = threadIdx.x >> 6;
  int lane = threadIdx.x & 63;
  int t = blockIdx.x * 4 + wave;

  float v[4];
  int idx[4];
#pragma unroll
  for (int j = 0; j < 4; ++j) {
    idx[j] = lane + 64 * j;
    float s = 0.f;
#pragma unroll
    for (int z = 0; z < LKZ_; ++z)
      s += lp[(size_t)z * T_ * NEXP_ + (size_t)t * NEXP_ + idx[j]];
    v[j] = s;
  }

  float topv[K_];
  int topi[K_];
#pragma unroll
  for (int k = 0; k < K_; ++k) {
    float bv = v[0];
    int bi = idx[0];
#pragma unroll
    for (int j = 1; j < 4; ++j)
      if (v[j] > bv || (v[j] == bv && idx[j] < bi)) { bv = v[j]; bi = idx[j]; }
#pragma unroll
    for (int off = 32; off > 0; off >>= 1) {
      float ov = __shfl_xor(bv, off);
      int oi = __shfl_xor(bi, off);
      if (ov > bv || (ov == bv && oi < bi)) { bv = ov; bi = oi; }
    }
    topv[k] = bv;
    topi[k] = bi;
#pragma unroll
    for (int j = 0; j < 4; ++j)
      if (idx[j] == bi) v[j] = -INFINITY;
  }

  float m = topv[0];
  float ev[K_];
  float s = 0.f;
#pragma unroll
  for (int k = 0; k < K_; ++k) { ev[k] = expf(topv[k] - m); s += ev[k]; }
  float inv = 1.f / s;
  if (lane < K_) {
    sel[t * K_ + lane] = topi[lane];
    wsm[t * K_ + lane] = ev[lane] * inv;
    atomicAdd(&cnt[topi[lane]], 1);
  }
}

// ---------------------------------------------------------------- scan + scatter (unchanged)
__global__ __launch_bounds__(256) void k_scan(const int* __restrict__ cnt,
                                              int* __restrict__ off) {
  __shared__ int s[NEXP_];
  int i = threadIdx.x;
  s[i] = cnt[i];
  __syncthreads();
  for (int d = 1; d < NEXP_; d <<= 1) {
    int v = (i >= d) ? s[i - d] : 0;
    __syncthreads();
    s[i] += v;
    __syncthreads();
  }
  off[i + 1] = s[i];
  if (i == 0) off[0] = 0;
}

__global__ __launch_bounds__(256) void k_scatter(const int* __restrict__ sel,
                                                 const float* __restrict__ wsm,
                                                 const int* __restrict__ off,
                                                 int* __restrict__ cur,
                                                 int* __restrict__ stok,
                                                 int* __restrict__ se,
                                                 float* __restrict__ sw,
                                                 int* __restrict__ ipos) {
  int f = blockIdx.x * 256 + threadIdx.x;
  int e = sel[f];
  int p = off[e] + atomicAdd(&cur[e], 1);
  stok[p] = f >> 3;
  se[p] = e;
  sw[p] = wsm[f];
  ipos[f] = p;
}

// ---------------------------------------------------------------- pre (MFMA, split-K 2)
// Pp[kz][g][t][r] = xb[t][dchunk] @ uin[g][dchunk][r].  grid (16, G, 2gu*2kz).
__global__ __launch_bounds__(256) void k_pre_mfma(const unsigned short* __restrict__ xb,
                                                  const unsigned short* __restrict__ uinT_g,
                                                  const unsigned short* __restrict__ uinT_u,
                                                  float* __restrict__ Pgp,
                                                  float* __restrict__ Pup) {
  int g = blockIdx.y;
  int gu = blockIdx.z >> 1, kz = blockIdx.z & 1;
  const unsigned short* U = gu ? uinT_u : uinT_g;  // [G][64(r)][1024(d)]
  float* P = gu ? Pup : Pgp;
  int t0 = blockIdx.x * 64;
  __shared__ short As[64 * LP_], Bs[64 * LP_];
  int tid = threadIdx.x, lane = tid & 63, ms = (tid >> 6) * 16;
  f32x4 acc[4] = {};
  int dlo = kz * (D_ / PKZ_);
  for (int dc = dlo; dc < dlo + D_ / PKZ_; dc += 64) {
    stage_tile(As, xb + (size_t)t0 * D_ + dc, D_, tid);
    stage_tile(Bs, U + (size_t)g * 64 * 1024 + dc, 1024, tid);
    __syncthreads();
    mma_strip(As, Bs, ms, lane, acc);
    __syncthreads();
  }
  int lm = lane & 15, lq = (lane >> 4) * 4;
#pragma unroll
  for (int nt = 0; nt < 4; ++nt)
#pragma unroll
    for (int r = 0; r < 4; ++r)
      P[((size_t)(kz * G_ + g) * T_ + t0 + ms + lq + r) * R_ + nt * 16 + lm] = acc[nt][r];
}

// ---------------------------------------------------------------- core gate/up (fp32) -> bf16
__global__ __launch_bounds__(256) void k_core_gu(const float* __restrict__ Pgp,
                                                 const float* __restrict__ Pup,
                                                 const float* __restrict__ core_g,
                                                 const float* __restrict__ core_u,
                                                 const int* __restrict__ stok,
                                                 const int* __restrict__ se,
                                                 unsigned short* __restrict__ xgb,
                                                 unsigned short* __restrict__ xub) {
  int pl = threadIdx.x >> 6;
  int o = threadIdx.x & 63;
  int p = blockIdx.x * 4 + pl;
  int e = se[p];
  int t = stok[p];
  int g = e >> 5;
  __shared__ float rg[4][64], ru[4][64];
  float sg = 0.f, su = 0.f;
#pragma unroll
  for (int kz = 0; kz < PKZ_; ++kz) {
    sg += Pgp[((size_t)(kz * G_ + g) * T_ + t) * R_ + o];
    su += Pup[((size_t)(kz * G_ + g) * T_ + t) * R_ + o];
  }
  rg[pl][o] = sg;
  ru[pl][o] = su;
  __syncthreads();
  const float* cg = core_g + (size_t)e * R_ * R_;
  const float* cu = core_u + (size_t)e * R_ * R_;
  float ag = 0.f, au = 0.f;
#pragma unroll 8
  for (int r = 0; r < R_; ++r) {
    ag = fmaf(rg[pl][r], cg[r * R_ + o], ag);
    au = fmaf(ru[pl][r], cu[r * R_ + o], au);
  }
  xgb[(size_t)p * R_ + o] = f2bf(ag);
  xub[(size_t)p * R_ + o] = f2bf(au);
}

// ---------------------------------------------------------------- act (MFMA): silu(xg@Uog)*(xu@Uou) -> bf16
// grid (16, G, DFF/64).  K=64 single chunk.
__global__ __launch_bounds__(256) void k_act_mfma(const unsigned short* __restrict__ xgb,
                                                  const unsigned short* __restrict__ xub,
                                                  const unsigned short* __restrict__ uoutT_g,
                                                  const unsigned short* __restrict__ uoutT_u,
                                                  const int* __restrict__ off,
                                                  unsigned short* __restrict__ act) {
  int g = blockIdx.y;
  int p0 = off[g * E_];
  int pend = off[g * E_ + E_];
  int ntiles = (pend - p0 + 63) >> 6;
  int c0 = blockIdx.z * 64;
  __shared__ short Ag[64 * LP_], Au[64 * LP_], Bg[64 * LP_], Bu[64 * LP_];
  int tid = threadIdx.x, lane = tid & 63, ms = (tid >> 6) * 16;
  int lm = lane & 15, lq = (lane >> 4) * 4;
  for (int tile = blockIdx.x; tile < ntiles; tile += gridDim.x) {
    int pbase = p0 + tile * 64;
    int rv = pend - pbase; if (rv > 64) rv = 64;
    stage_tile_guard(Ag, xgb + (size_t)pbase * R_, R_, rv, tid);
    stage_tile_guard(Au, xub + (size_t)pbase * R_, R_, rv, tid);
    stage_tile(Bg, uoutT_g + ((size_t)g * DFF_ + c0) * R_, R_, tid);
    stage_tile(Bu, uoutT_u + ((size_t)g * DFF_ + c0) * R_, R_, tid);
    __syncthreads();
    f32x4 accg[4] = {}, accu[4] = {};
    mma_strip(Ag, Bg, ms, lane, accg);
    mma_strip(Au, Bu, ms, lane, accu);
    // silu(gate)*up -> bf16 into Ag (wave-private rows [ms,ms+16))
#pragma unroll
    for (int nt = 0; nt < 4; ++nt)
#pragma unroll
      for (int r = 0; r < 4; ++r) {
        float gv = accg[nt][r];
        float a = gv / (1.f + expf(-gv)) * accu[nt][r];
        Ag[(ms + lq + r) * LP_ + nt * 16 + lm] = (short)f2bf(a);
      }
    __syncthreads();
    for (int idx = tid; idx < 512; idx += 256) {
      int r = idx >> 3, c8 = (idx & 7) << 3;
      if (r < rv)
        *(uint4*)&act[((size_t)(pbase + r)) * DFF_ + c0 + c8] = *(const uint4*)&Ag[r * LP_ + c8];
    }
    __syncthreads();
  }
}

// ---------------------------------------------------------------- down (MFMA, split-K 4)
// xdp[kz][p][r] = act[p][cchunk] @ uin_down[g][cchunk][r].  grid (16, G, DKZ_).
__global__ __launch_bounds__(256) void k_down_mfma(const unsigned short* __restrict__ act,
                                                   const unsigned short* __restrict__ uinT_d,
                                                   const int* __restrict__ off,
                                                   float* __restrict__ xdp) {
  int g = blockIdx.y;
  int kz = blockIdx.z;
  int p0 = off[g * E_];
  int pend = off[g * E_ + E_];
  int ntiles = (pend - p0 + 63) >> 6;
  __shared__ short As[64 * LP_], Bs[64 * LP_];
  int tid = threadIdx.x, lane = tid & 63, ms = (tid >> 6) * 16;
  int lm = lane & 15, lq = (lane >> 4) * 4;
  int clo = kz * (DFF_ / DKZ_);
  for (int tile = blockIdx.x; tile < ntiles; tile += gridDim.x) {
    int pbase = p0 + tile * 64;
    int rv = pend - pbase; if (rv > 64) rv = 64;
    f32x4 acc[4] = {};
    for (int cc = clo; cc < clo + DFF_ / DKZ_; cc += 64) {
      stage_tile_guard(As, act + (size_t)pbase * DFF_ + cc, DFF_, rv, tid);
      stage_tile(Bs, uinT_d + (size_t)g * 64 * 1024 + cc, 1024, tid);
      __syncthreads();
      mma_strip(As, Bs, ms, lane, acc);
      __syncthreads();
    }
#pragma unroll
    for (int nt = 0; nt < 4; ++nt)
#pragma unroll
      for (int r = 0; r < 4; ++r) {
        int p = pbase + ms + lq + r;
        if (p < pend) xdp[((size_t)kz * F_ + p) * R_ + nt * 16 + lm] = acc[nt][r];
      }
  }
}

// ---------------------------------------------------------------- fold + down core (fp32) -> bf16
__global__ __launch_bounds__(256) void k_core_down(const float* __restrict__ xdp,
                                                   const float* __restrict__ core_d,
                                                   const int* __restrict__ se,
                                                   unsigned short* __restrict__ xd2b) {
  int pl = threadIdx.x >> 6;
  int o = threadIdx.x & 63;
  int p = blockIdx.x * 4 + pl;
  int e = se[p];
  __shared__ float rg[4][64];
  float s = 0.f;
#pragma unroll
  for (int kz = 0; kz < DKZ_; ++kz) s += xdp[((size_t)kz * F_ + p) * R_ + o];
  rg[pl][o] = s;
  __syncthreads();
  const float* cd = core_d + (size_t)e * R_ * R_;
  float a = 0.f;
#pragma unroll 8
  for (int r = 0; r < R_; ++r) a = fmaf(rg[pl][r], cd[r * R_ + o], a);
  xd2b[(size_t)p * R_ + o] = f2bf(a);
}

// ---------------------------------------------------------------- outf (MFMA): w[p]*(xd2 @ uout_down[g])
// grid (16, G, D/64).  K=64 single chunk; fp32 output staged via LDS.
__global__ __launch_bounds__(256) void k_outf_mfma(const unsigned short* __restrict__ xd2b,
                                                   const unsigned short* __restrict__ uoutT_d,
                                                   const int* __restrict__ off,
                                                   const float* __restrict__ sw,
                                                   float* __restrict__ outf) {
  int g = blockIdx.y;
  int p0 = off[g * E_];
  int pend = off[g * E_ + E_];
  int ntiles = (pend - p0 + 63) >> 6;
  int c0 = blockIdx.z * 64;
  __shared__ short As[64 * LP_], Bs[64 * LP_];
  __shared__ float Os[64 * 68];
  int tid = threadIdx.x, lane = tid & 63, ms = (tid >> 6) * 16;
  int lm = lane & 15, lq = (lane >> 4) * 4;
  for (int tile = blockIdx.x; tile < ntiles; tile += gridDim.x) {
    int pbase = p0 + tile * 64;
    int rv = pend - pbase; if (rv > 64) rv = 64;
    stage_tile_guard(As, xd2b + (size_t)pbase * R_, R_, rv, tid);
    stage_tile(Bs, uoutT_d + ((size_t)g * D_ + c0) * R_, R_, tid);
    __syncthreads();
    f32x4 acc[4] = {};
    mma_strip(As, Bs, ms, lane, acc);
    float wv[4];
#pragma unroll
    for (int r = 0; r < 4; ++r) {
      int p = pbase + ms + lq + r;
      wv[r] = (p < pend) ? sw[p] : 0.f;
    }
#pragma unroll
    for (int nt = 0; nt < 4; ++nt)
#pragma unroll
      for (int r = 0; r < 4; ++r)
        Os[(ms + lq + r) * 68 + nt * 16 + lm] = acc[nt][r] * wv[r];
    __syncthreads();
    for (int idx = tid; idx < 1024; idx += 256) {
      int r = idx >> 4, c4 = (idx & 15) << 2;
      if (r < rv)
        *(float4*)&outf[(size_t)(pbase + r) * D_ + c0 + c4] = *(const float4*)&Os[r * 68 + c4];
    }
    __syncthreads();
  }
}

// ---------------------------------------------------------------- gather: out[t] = sum_k outf[ipos[t*8+k]]
__global__ __launch_bounds__(256) void k_gather(const float* __restrict__ outf,
                                                const int* __restrict__ ipos,
                                                float* __restrict__ out) {
  int t = blockIdx.x;
  __shared__ int pos[K_];
  if (threadIdx.x < K_) pos[threadIdx.x] = ipos[t * K_ + threadIdx.x];
  __syncthreads();
  int c = threadIdx.x * 4;
  float4 s = make_float4(0.f, 0.f, 0.f, 0.f);
#pragma unroll
  for (int k = 0; k < K_; ++k) {
    float4 v = *(const float4*)(outf + (size_t)pos[k] * D_ + c);
    s.x += v.x; s.y += v.y; s.z += v.z; s.w += v.w;
  }
  *(float4*)(out + (size_t)t * D_ + c) = s;
}

// ================================================================ launch
extern "C" void kernel_launch(void* const* d_in, const int* in_sizes, int n_in,
                              void* d_out, int out_size, void* d_ws, size_t ws_size,
                              hipStream_t stream) {
  const float* x = (const float*)d_in[0];
  const float* Wg = (const float*)d_in[1];
  const float* uin_gate = (const float*)d_in[2];
  const float* core_gate = (const float*)d_in[3];
  const float* uout_gate = (const float*)d_in[4];
  const float* uin_up = (const float*)d_in[5];
  const float* core_up = (const float*)d_in[6];
  const float* uout_up = (const float*)d_in[7];
  const float* uin_down = (const float*)d_in[8];
  const float* core_down = (const float*)d_in[9];
  const float* uout_down = (const float*)d_in[10];
  float* out = (float*)d_out;

  char* ws = (char*)d_ws;
  size_t o = 0;
  auto alloc = [&](size_t bytes) { size_t r = o; o = (o + bytes + 255) & ~(size_t)255; return r; };
  size_t o_lp = alloc((size_t)LKZ_ * T_ * NEXP_ * 4);           // 4 MB
  size_t o_sel = alloc(F_ * 4);
  size_t o_wsm = alloc(F_ * 4);
  size_t o_cnt = alloc(NEXP_ * 4);
  size_t o_cur = alloc(NEXP_ * 4);
  size_t o_off = alloc((NEXP_ + 1) * 4);
  size_t o_stok = alloc(F_ * 4);
  size_t o_se = alloc(F_ * 4);
  size_t o_sw = alloc(F_ * 4);
  size_t o_ipos = alloc(F_ * 4);
  size_t o_xb = alloc((size_t)T_ * D_ * 2);                     // 2 MB
  size_t o_uinT_g = alloc((size_t)G_ * 64 * 1024 * 2);          // 1 MB each
  size_t o_uinT_u = alloc((size_t)G_ * 64 * 1024 * 2);
  size_t o_uinT_d = alloc((size_t)G_ * 64 * 1024 * 2);
  size_t o_uoutT_g = alloc((size_t)G_ * 1024 * 64 * 2);
  size_t o_uoutT_u = alloc((size_t)G_ * 1024 * 64 * 2);
  size_t o_uoutT_d = alloc((size_t)G_ * 1024 * 64 * 2);
  size_t o_xgb = alloc((size_t)F_ * R_ * 2);                    // 1 MB
  size_t o_xub = alloc((size_t)F_ * R_ * 2);
  size_t o_xd2b = alloc((size_t)F_ * R_ * 2);
  // union region (32 MB): outf overlays {act, xdp, pgp, pup}, all dead by k_outf
  size_t o_union = alloc((size_t)F_ * D_ * 4);
  size_t o_act = o_union;                                        // 16 MB bf16
  size_t o_xdp = o_union + (size_t)16 * 1024 * 1024;             // 8 MB fp32
  size_t o_pgp = o_union + (size_t)24 * 1024 * 1024;             // 4 MB fp32
  size_t o_pup = o_union + (size_t)28 * 1024 * 1024;             // 4 MB fp32
  (void)ws_size;

  float* lp = (float*)(ws + o_lp);
  int* sel = (int*)(ws + o_sel);
  float* wsm = (float*)(ws + o_wsm);
  int* cnt = (int*)(ws + o_cnt);
  int* cur = (int*)(ws + o_cur);
  int* off = (int*)(ws + o_off);
  int* stok = (int*)(ws + o_stok);
  int* se = (int*)(ws + o_se);
  float* sw = (float*)(ws + o_sw);
  int* ipos = (int*)(ws + o_ipos);
  unsigned short* xb = (unsigned short*)(ws + o_xb);
  unsigned short* uinT_g = (unsigned short*)(ws + o_uinT_g);
  unsigned short* uinT_u = (unsigned short*)(ws + o_uinT_u);
  unsigned short* uinT_d = (unsigned short*)(ws + o_uinT_d);
  unsigned short* uoutT_g = (unsigned short*)(ws + o_uoutT_g);
  unsigned short* uoutT_u = (unsigned short*)(ws + o_uoutT_u);
  unsigned short* uoutT_d = (unsigned short*)(ws + o_uoutT_d);
  unsigned short* xgb = (unsigned short*)(ws + o_xgb);
  unsigned short* xub = (unsigned short*)(ws + o_xub);
  unsigned short* xd2b = (unsigned short*)(ws + o_xd2b);
  unsigned short* act = (unsigned short*)(ws + o_act);
  float* xdp = (float*)(ws + o_xdp);
  float* pgp = (float*)(ws + o_pgp);
  float* pup = (float*)(ws + o_pup);
  float* outf = (float*)(ws + o_union);

  hipMemsetAsync(cnt, 0, NEXP_ * 4, stream);
  hipMemsetAsync(cur, 0, NEXP_ * 4, stream);

  k_cast_x<<<T_ * D_ / 1024, 256, 0, stream>>>(x, xb);
  k_castT<<<dim3(16, G_, 6), 256, 0, stream>>>(uin_gate, uin_up, uin_down,
                                               uout_gate, uout_up, uout_down,
                                               uinT_g, uinT_u, uinT_d,
                                               uoutT_g, uoutT_u, uoutT_d);
  k_logits<<<dim3(T_ / 4, LKZ_), 256, 0, stream>>>(x, Wg, lp);
  k_topk<<<T_ / 4, 256, 0, stream>>>(lp, sel, wsm, cnt);
  k_scan<<<1, 256, 0, stream>>>(cnt, off);
  k_scatter<<<F_ / 256, 256, 0, stream>>>(sel, wsm, off, cur, stok, se, sw, ipos);
  k_pre_mfma<<<dim3(T_ / 64, G_, 2 * PKZ_), 256, 0, stream>>>(xb, uinT_g, uinT_u, pgp, pup);
  k_core_gu<<<F_ / 4, 256, 0, stream>>>(pgp, pup, core_gate, core_up, stok, se, xgb, xub);
  k_act_mfma<<<dim3(16, G_, DFF_ / 64), 256, 0, stream>>>(xgb, xub, uoutT_g, uoutT_u, off, act);
  k_down_mfma<<<dim3(16, G_, DKZ_), 256, 0, stream>>>(act, uinT_d, off, xdp);
  k_core_down<<<F_ / 4, 256, 0, stream>>>(xdp, core_down, se, xd2b);
  k_outf_mfma<<<dim3(16, G_, D_ / 64), 256, 0, stream>>>(xd2b, uoutT_d, off, sw, outf);
  k_gather<<<T_, 256, 0, stream>>>(outf, ipos, out);
}